// Round 4
// baseline (626.568 us; speedup 1.0000x reference)
//
#include <hip/hip_runtime.h>

typedef unsigned short u16;
typedef __attribute__((ext_vector_type(8))) short short8;
typedef __attribute__((ext_vector_type(4))) float floatx4;

#define B_  16
#define S_  384
#define D_  768
#define H_  12
#define DH_ 64
#define FF_ 3072

__device__ __forceinline__ float b2f(u16 h) { return __uint_as_float(((unsigned)h) << 16); }
__device__ __forceinline__ u16 f2b(float f) {
  unsigned u = __float_as_uint(f);
  u += 0x7fffu + ((u >> 16) & 1u);
  return (u16)(u >> 16);
}

// async global->LDS, 16B per lane; LDS dest = uniform base + lane*16
__device__ __forceinline__ void gload16(const u16* g, u16* l) {
  __builtin_amdgcn_global_load_lds(
      (const __attribute__((address_space(1))) unsigned int*)g,
      (__attribute__((address_space(3))) unsigned int*)l, 16, 0, 0);
}

// diagnostic sentinel: ws too small
__global__ __launch_bounds__(256) void fill_sentinel(u16* out, int n) {
  int i = blockIdx.x * 256 + threadIdx.x;
  if (i < n) out[i] = 0x42DE;  // bf16 111.0
}

// ---------------- dtype detect: bf16 data has no exponent field >= 0xC0 ----------------
__global__ __launch_bounds__(256) void detect_dtype(const u16* __restrict__ x, int* flag) {
  __shared__ int cnt;
  if (threadIdx.x == 0) cnt = 0;
  __syncthreads();
  int c = 0;
  for (int i = threadIdx.x; i < 8192; i += 256) {
    const unsigned e = (x[i] >> 7) & 0xFFu;
    if (e >= 0xC0u) ++c;
  }
  atomicAdd(&cnt, c);
  __syncthreads();
  if (threadIdx.x == 0) *flag = (cnt > 64) ? 1 : 0;  // 1 = inputs are fp32
}

// ---------------- input conversion (dual dtype -> bf16) ----------------
__global__ __launch_bounds__(256) void convert_in(const void* __restrict__ src,
                                                  u16* __restrict__ dst, int n,
                                                  const int* __restrict__ flag) {
  const int i = blockIdx.x * 256 + threadIdx.x;
  if (i >= n) return;
  if (*flag) dst[i] = f2b(((const float*)src)[i]);
  else dst[i] = ((const u16*)src)[i];
}

// ---------------- weight transpose + convert: out[c][r] = in[r][c] ----------------
__global__ __launch_bounds__(256) void transpose_cv(const void* __restrict__ in,
                                                    u16* __restrict__ out, int R, int C,
                                                    const int* __restrict__ flag) {
  __shared__ u16 t[32][33];
  const int f32 = *flag;
  const int bc = blockIdx.x * 32, br = blockIdx.y * 32;
  const int tx = threadIdx.x & 31, ty = threadIdx.x >> 5;
  for (int i = ty; i < 32; i += 8) {
    const size_t idx = (size_t)(br + i) * C + bc + tx;
    t[i][tx] = f32 ? f2b(((const float*)in)[idx]) : ((const u16*)in)[idx];
  }
  __syncthreads();
  for (int i = ty; i < 32; i += 8) out[(size_t)(bc + i) * R + br + tx] = t[tx][i];
}

// ---------------- GEMM: C[M,N] = A[M,K] @ Bt[N,K]^T, async staging ----------------
enum { F_BIAS = 1, F_RELU = 2, F_RES = 4, F_QKV = 8 };

// TMxTN block tile; 4 waves each computing WMxWN; BK=32.
// LDS layout (quad-major): seg(region,row,quad) at (quad*T + row)*8 u16 — contiguous
// in global_load_lds order AND conflict-light for ds_read_b128 frag reads.
template <int TM, int TN, int WM, int WN, int FLAGS>
__global__ __launch_bounds__(256) void gemm2(
    const u16* __restrict__ A, const u16* __restrict__ Bt,
    u16* __restrict__ out0, u16* __restrict__ out1,
    u16* __restrict__ out2, u16* __restrict__ out3,
    const u16* __restrict__ bias0, const u16* __restrict__ bias1,
    const u16* __restrict__ res, int M, int N, int K) {
  constexpr int WAVES_M = TM / WM;
  constexpr int MT = WM / 16, NT = WN / 16;
  constexpr int NI = (TM + TN) / 64;  // wave-issues per wave per k-step
  static_assert((TM / WM) * (TN / WN) == 4, "4 waves");
  __shared__ u16 SMEM[(TM + TN) * 32];

  const int m0 = blockIdx.y * TM;
  const int n0 = blockIdx.x * TN;
  const int tid = threadIdx.x;
  const int wid = tid >> 6, lane = tid & 63;
  const int wm = (wid % WAVES_M) * WM, wn = (wid / WAVES_M) * WN;
  const int lm = lane & 15, quad = lane >> 4;

  floatx4 acc[MT][NT];
#pragma unroll
  for (int i = 0; i < MT; ++i)
#pragma unroll
    for (int j = 0; j < NT; ++j) acc[i][j] = (floatx4){0.f, 0.f, 0.f, 0.f};

  // staging sources (advance by 32 u16 per step); LDS dests fixed
  const u16* srcs[NI];
  u16* ldst[NI];
#pragma unroll
  for (int i = 0; i < NI; ++i) {
    const int j = wid + 4 * i;
    const int seg = j * 64 + lane;
    const u16* p;
    if (seg < TM * 4) {
      const int q = seg / TM, row = seg - q * TM;
      int ga = m0 + row;
      if (ga > M - 1) ga = M - 1;  // clamp; garbage row guarded in epilogue
      p = A + (size_t)ga * K + q * 8;
    } else {
      const int s2 = seg - TM * 4;
      const int q = s2 / TN, row = s2 - q * TN;
      p = Bt + (size_t)(n0 + row) * K + q * 8;
    }
    srcs[i] = p;
    ldst[i] = SMEM + j * 512;
  }
  // fragment read pointers (fixed across steps)
  const u16* apf[MT];
  const u16* bpf[NT];
#pragma unroll
  for (int t = 0; t < MT; ++t) apf[t] = SMEM + ((size_t)(quad * TM + wm + t * 16 + lm)) * 8;
#pragma unroll
  for (int t = 0; t < NT; ++t)
    bpf[t] = SMEM + (size_t)TM * 32 + ((size_t)(quad * TN + wn + t * 16 + lm)) * 8;

  for (int k0 = 0; k0 < K; k0 += 32) {
#pragma unroll
    for (int i = 0; i < NI; ++i) {
      gload16(srcs[i], ldst[i]);
      srcs[i] += 32;
    }
    __syncthreads();
    short8 af[MT], bf[NT];
#pragma unroll
    for (int t = 0; t < MT; ++t) af[t] = *(const short8*)apf[t];
#pragma unroll
    for (int t = 0; t < NT; ++t) bf[t] = *(const short8*)bpf[t];
#pragma unroll
    for (int tm = 0; tm < MT; ++tm)
#pragma unroll
      for (int tn = 0; tn < NT; ++tn)
        acc[tm][tn] = __builtin_amdgcn_mfma_f32_16x16x32_bf16(af[tm], bf[tn], acc[tm][tn], 0, 0, 0);
    __syncthreads();
  }

#pragma unroll
  for (int tm = 0; tm < MT; ++tm) {
#pragma unroll
    for (int tn = 0; tn < NT; ++tn) {
      const int gcol = n0 + wn + tn * 16 + lm;
#pragma unroll
      for (int r = 0; r < 4; ++r) {
        const int grow = m0 + wm + tm * 16 + quad * 4 + r;
        if (grow >= M) continue;
        float val = acc[tm][tn][r];
        if (FLAGS & F_QKV) {
          const int region = gcol / 768;  // block-uniform (TN | 768)
          const int c = gcol - region * 768;
          if (region == 0) {
            out0[(size_t)grow * 768 + c] = f2b(val + b2f(bias0[c]));  // q + u
            out1[(size_t)grow * 768 + c] = f2b(val + b2f(bias1[c]));  // q + v
          } else if (region == 1) {
            out2[(size_t)grow * 768 + c] = f2b(val);                  // k
          } else {
            const int bb = grow / S_, s = grow - bb * S_;
            out3[((size_t)bb * D_ + c) * S_ + s] = f2b(val);          // v transposed
          }
        } else {
          if (FLAGS & F_BIAS) val += b2f(bias0[gcol]);
          if (FLAGS & F_RES) val += b2f(res[(size_t)grow * N + gcol]);
          if (FLAGS & F_RELU) val = fmaxf(val, 0.f);
          out0[(size_t)grow * N + gcol] = f2b(val);
        }
      }
    }
  }
}

// ---------------- fused rel-pos attention ----------------
__global__ __launch_bounds__(256) void attn_kernel(
    const u16* __restrict__ qu, const u16* __restrict__ qv,
    const u16* __restrict__ kb, const u16* __restrict__ vt,
    const u16* __restrict__ rb, u16* __restrict__ attn) {
  __shared__ float sc[16][384];
  __shared__ u16 p[16][392];
  __shared__ float red[16][16];
  __shared__ float rmax[16], rsum[16];

  const int qt = blockIdx.x, bh = blockIdx.y;
  const int b = bh / H_, h = bh % H_;
  const int i0 = qt * 16;
  const int tid = threadIdx.x, wid = tid >> 6, lane = tid & 63;
  const int lm = lane & 15, quad = lane >> 4;
  float* scf = &sc[0][0];

  for (int i = tid; i < 16 * 384; i += 256) scf[i] = 0.f;
  __syncthreads();

  const size_t qrow = ((size_t)(b * S_ + i0 + lm)) * D_ + h * DH_;
  {
    const short8 a0 = *(const short8*)(qv + qrow + quad * 8);
    const short8 a1 = *(const short8*)(qv + qrow + 32 + quad * 8);
    for (int tt = wid; tt < 25; tt += 4) {
      const int trel = tt * 16 + lm;
      int t = i0 + trel;
      if (t > 766) t = 766;
      const size_t rrow = (size_t)t * D_ + h * DH_;
      const short8 b0 = *(const short8*)(rb + rrow + quad * 8);
      const short8 b1 = *(const short8*)(rb + rrow + 32 + quad * 8);
      floatx4 e = (floatx4){0.f, 0.f, 0.f, 0.f};
      e = __builtin_amdgcn_mfma_f32_16x16x32_bf16(a0, b0, e, 0, 0, 0);
      e = __builtin_amdgcn_mfma_f32_16x16x32_bf16(a1, b1, e, 0, 0, 0);
#pragma unroll
      for (int r = 0; r < 4; ++r) {
        const int row = quad * 4 + r;
        const int j = row - trel + 383;
        if (j >= 0 && j < 384) sc[row][j] += e[r];
      }
    }
  }
  __syncthreads();
  {
    const short8 a0 = *(const short8*)(qu + qrow + quad * 8);
    const short8 a1 = *(const short8*)(qu + qrow + 32 + quad * 8);
    for (int q = 0; q < 6; ++q) {
      const int j0 = (wid * 6 + q) * 16;
      const size_t krow = ((size_t)(b * S_ + j0 + lm)) * D_ + h * DH_;
      const short8 b0 = *(const short8*)(kb + krow + quad * 8);
      const short8 b1 = *(const short8*)(kb + krow + 32 + quad * 8);
      floatx4 e = (floatx4){0.f, 0.f, 0.f, 0.f};
      e = __builtin_amdgcn_mfma_f32_16x16x32_bf16(a0, b0, e, 0, 0, 0);
      e = __builtin_amdgcn_mfma_f32_16x16x32_bf16(a1, b1, e, 0, 0, 0);
#pragma unroll
      for (int r = 0; r < 4; ++r) {
        const int row = quad * 4 + r;
        sc[row][j0 + lm] = (sc[row][j0 + lm] + e[r]) * 0.125f;
      }
    }
  }
  __syncthreads();
  {
    const int row = tid >> 4, sub = tid & 15;
    float lmax = -1e30f;
    for (int cc = 0; cc < 24; ++cc) lmax = fmaxf(lmax, sc[row][sub + cc * 16]);
    red[row][sub] = lmax;
    __syncthreads();
    if (sub == 0) {
      float m = red[row][0];
      for (int i = 1; i < 16; ++i) m = fmaxf(m, red[row][i]);
      rmax[row] = m;
    }
    __syncthreads();
    const float m = rmax[row];
    float lsum = 0.f;
    for (int cc = 0; cc < 24; ++cc) {
      const int c = sub + cc * 16;
      const float e = __expf(sc[row][c] - m);
      p[row][c] = f2b(e);
      lsum += e;
    }
    red[row][sub] = lsum;
    __syncthreads();
    if (sub == 0) {
      float s2 = 0.f;
      for (int i = 0; i < 16; ++i) s2 += red[row][i];
      rsum[row] = s2;
    }
    __syncthreads();
  }
  floatx4 o[4];
#pragma unroll
  for (int nt = 0; nt < 4; ++nt) o[nt] = (floatx4){0.f, 0.f, 0.f, 0.f};
  for (int kk = 0; kk < 3; ++kk) {
    const int kbase = wid * 96 + kk * 32;
    const short8 af = *(const short8*)(&p[lm][kbase + quad * 8]);
#pragma unroll
    for (int nt = 0; nt < 4; ++nt) {
      const size_t vrow = ((size_t)(b * D_ + h * DH_ + nt * 16 + lm)) * S_;
      const short8 bv = *(const short8*)(vt + vrow + kbase + quad * 8);
      o[nt] = __builtin_amdgcn_mfma_f32_16x16x32_bf16(af, bv, o[nt], 0, 0, 0);
    }
  }
  __syncthreads();
#pragma unroll
  for (int nt = 0; nt < 4; ++nt)
#pragma unroll
    for (int r = 0; r < 4; ++r) {
      const int row = quad * 4 + r, dh = nt * 16 + lm;
      scf[wid * 1024 + row * 64 + dh] = o[nt][r];
    }
  __syncthreads();
  for (int t = tid; t < 1024; t += 256) {
    const int row = t >> 6, dh = t & 63;
    float v = scf[row * 64 + dh] + scf[1024 + row * 64 + dh] +
              scf[2048 + row * 64 + dh] + scf[3072 + row * 64 + dh];
    v /= rsum[row];
    attn[((size_t)(b * S_ + i0 + row)) * D_ + h * DH_ + dh] = f2b(v);
  }
}

// ---------------- row layernorm ----------------
__global__ __launch_bounds__(256) void ln_kernel(const u16* __restrict__ y,
                                                 const u16* __restrict__ g,
                                                 const u16* __restrict__ bb,
                                                 void* __restrict__ outv,
                                                 const int* __restrict__ flag, int dual) {
  const int row = blockIdx.x * 4 + (threadIdx.x >> 6);
  const int lane = threadIdx.x & 63;
  const u16* yr = y + (size_t)row * D_;
  float vbuf[12], s = 0.f, s2 = 0.f;
#pragma unroll
  for (int i = 0; i < 12; ++i) {
    const float x = b2f(yr[lane + i * 64]);
    vbuf[i] = x;
    s += x;
    s2 += x * x;
  }
#pragma unroll
  for (int off = 32; off; off >>= 1) {
    s += __shfl_down(s, off);
    s2 += __shfl_down(s2, off);
  }
  s = __shfl(s, 0);
  s2 = __shfl(s2, 0);
  const float mean = s * (1.f / 768.f);
  const float var = s2 * (1.f / 768.f) - mean * mean;
  const float inv = rsqrtf(var + 1e-5f);
  const int f32out = dual && *flag;
#pragma unroll
  for (int i = 0; i < 12; ++i) {
    const int c = lane + i * 64;
    const float val = (vbuf[i] - mean) * inv * b2f(g[c]) + b2f(bb[c]);
    if (f32out) ((float*)outv)[(size_t)row * D_ + c] = val;
    else ((u16*)outv)[(size_t)row * D_ + c] = f2b(val);
  }
}

// ---------------- host ----------------
extern "C" void kernel_launch(void* const* d_in, const int* in_sizes, int n_in,
                              void* d_out, int out_size, void* d_ws, size_t ws_size,
                              hipStream_t stream) {
  const void* x    = d_in[0];
  const void* pe   = d_in[1];
  const void* Wq   = d_in[2];
  const void* Wk   = d_in[3];
  const void* Wv   = d_in[4];
  const void* Wr   = d_in[5];
  const void* ub   = d_in[6];
  const void* vb   = d_in[7];
  const void* Wo   = d_in[8];
  const void* ln1g = d_in[9];
  const void* ln1b = d_in[10];
  const void* ln2g = d_in[11];
  const void* ln2b = d_in[12];
  const void* W1   = d_in[13];
  const void* b1   = d_in[14];
  const void* W2   = d_in[15];
  const void* b2   = d_in[16];
  char* ws = (char*)d_ws;

  constexpr int N_X  = B_ * S_ * D_;
  constexpr int N_PE = (2 * S_ - 1) * D_;

  constexpr size_t O_W   = 0;
  constexpr size_t O_SM  = 15335424;
  constexpr size_t O_XB  = 15368192;
  constexpr size_t O_QU  = 24805376;
  constexpr size_t O_QV  = 34242560;
  constexpr size_t O_KB  = 43679744;
  constexpr size_t O_VT  = 53116928;
  constexpr size_t O_RB  = 62554112;
  constexpr size_t NEEDED = 63733760;

  if (ws_size < NEEDED) {
    fill_sentinel<<<(out_size + 255) / 256, 256, 0, stream>>>((u16*)d_out, out_size);
    return;
  }

  int* flag = (int*)(ws + O_SM);
  u16* ubc  = (u16*)(ws + O_SM + 128);
  u16* vbc  = (u16*)(ws + O_SM + 1664);
  u16* b1c  = (u16*)(ws + O_SM + 3200);
  u16* b2c  = (u16*)(ws + O_SM + 9344);
  u16* g1c  = (u16*)(ws + O_SM + 10880);
  u16* be1c = (u16*)(ws + O_SM + 12416);
  u16* g2c  = (u16*)(ws + O_SM + 13952);
  u16* be2c = (u16*)(ws + O_SM + 15488);

  u16* wtq = (u16*)(ws + O_W);   // wtq|wtk|wtv contiguous => fused QKV B (N=2304)
  u16* wtk = wtq + (size_t)D_ * D_;
  u16* wtv = wtk + (size_t)D_ * D_;
  u16* wtr = wtv + (size_t)D_ * D_;
  u16* wto = wtr + (size_t)D_ * D_;
  u16* wt1 = wto + (size_t)D_ * D_;
  u16* wt2 = wt1 + (size_t)D_ * FF_;

  u16* xb  = (u16*)(ws + O_XB);
  u16* quB = (u16*)(ws + O_QU);
  u16* peb = (u16*)(ws + O_QV);
  u16* qvB = (u16*)(ws + O_QV);
  u16* kbB = (u16*)(ws + O_KB);
  u16* vtB = (u16*)(ws + O_VT);
  u16* rbB = (u16*)(ws + O_RB);
  u16* atB = (u16*)d_out;
  u16* y1B = xb;
  u16* x1B = (u16*)(ws + O_VT);
  u16* ffB = xb;
  u16* y2B = x1B;

  detect_dtype<<<1, 256, 0, stream>>>((const u16*)x, flag);
  convert_in<<<(N_X + 255) / 256, 256, 0, stream>>>(x, xb, N_X, flag);
  convert_in<<<(N_PE + 255) / 256, 256, 0, stream>>>(pe, peb, N_PE, flag);
  convert_in<<<3, 256, 0, stream>>>(ub, ubc, 768, flag);
  convert_in<<<3, 256, 0, stream>>>(vb, vbc, 768, flag);
  convert_in<<<12, 256, 0, stream>>>(b1, b1c, 3072, flag);
  convert_in<<<3, 256, 0, stream>>>(b2, b2c, 768, flag);
  convert_in<<<3, 256, 0, stream>>>(ln1g, g1c, 768, flag);
  convert_in<<<3, 256, 0, stream>>>(ln1b, be1c, 768, flag);
  convert_in<<<3, 256, 0, stream>>>(ln2g, g2c, 768, flag);
  convert_in<<<3, 256, 0, stream>>>(ln2b, be2c, 768, flag);
  transpose_cv<<<dim3(24, 24), 256, 0, stream>>>(Wq, wtq, D_, D_, flag);
  transpose_cv<<<dim3(24, 24), 256, 0, stream>>>(Wk, wtk, D_, D_, flag);
  transpose_cv<<<dim3(24, 24), 256, 0, stream>>>(Wv, wtv, D_, D_, flag);
  transpose_cv<<<dim3(24, 24), 256, 0, stream>>>(Wr, wtr, D_, D_, flag);
  transpose_cv<<<dim3(24, 24), 256, 0, stream>>>(Wo, wto, D_, D_, flag);
  transpose_cv<<<dim3(96, 24), 256, 0, stream>>>(W1, wt1, D_, FF_, flag);
  transpose_cv<<<dim3(24, 96), 256, 0, stream>>>(W2, wt2, FF_, D_, flag);

  // r-proj (before qv overwrites peb): M=767, 64x64 tiles -> 144 blocks
  gemm2<64, 64, 32, 32, 0><<<dim3(12, 12), 256, 0, stream>>>(
      peb, wtr, rbB, nullptr, nullptr, nullptr, nullptr, nullptr, nullptr,
      2 * S_ - 1, D_, D_);
  // fused QKV: N=2304, 128x128 -> 864 blocks
  gemm2<128, 128, 64, 64, F_QKV><<<dim3(18, 48), 256, 0, stream>>>(
      xb, wtq, quB, qvB, kbB, vtB, ubc, vbc, nullptr, B_ * S_, 2304, D_);
  // attention -> d_out scratch
  attn_kernel<<<dim3(S_ / 16, B_ * H_), 256, 0, stream>>>(quB, qvB, kbB, vtB, rbB, atB);
  // Wo + residual: 128x64 -> 576 blocks
  gemm2<128, 64, 32, 64, F_RES><<<dim3(12, 48), 256, 0, stream>>>(
      atB, wto, y1B, nullptr, nullptr, nullptr, nullptr, nullptr, xb, B_ * S_, D_, D_);
  ln_kernel<<<B_ * S_ / 4, 256, 0, stream>>>(y1B, g1c, be1c, x1B, flag, 0);
  // FFN1: 128x128 -> 1152 blocks
  gemm2<128, 128, 64, 64, F_BIAS | F_RELU><<<dim3(24, 48), 256, 0, stream>>>(
      x1B, wt1, ffB, nullptr, nullptr, nullptr, b1c, nullptr, nullptr, B_ * S_, FF_, D_);
  // FFN2: K=3072, 128x64 -> 576 blocks
  gemm2<128, 64, 32, 64, F_BIAS | F_RES><<<dim3(12, 48), 256, 0, stream>>>(
      ffB, wt2, y2B, nullptr, nullptr, nullptr, b2c, nullptr, x1B, B_ * S_, D_, FF_);
  ln_kernel<<<B_ * S_ / 4, 256, 0, stream>>>(y2B, g2c, be2c, d_out, flag, 1);
}

// Round 5
// 503.672 us; speedup vs baseline: 1.2440x; 1.2440x over previous
//
#include <hip/hip_runtime.h>

typedef unsigned short u16;
typedef __attribute__((ext_vector_type(8))) short short8;
typedef __attribute__((ext_vector_type(4))) float floatx4;

#define B_  16
#define S_  384
#define D_  768
#define H_  12
#define DH_ 64
#define FF_ 3072

__device__ __forceinline__ float b2f(u16 h) { return __uint_as_float(((unsigned)h) << 16); }
__device__ __forceinline__ u16 f2b(float f) {
  unsigned u = __float_as_uint(f);
  u += 0x7fffu + ((u >> 16) & 1u);
  return (u16)(u >> 16);
}

// async global->LDS, 16B/lane; LDS dest = wave-uniform base, HW adds lane*16
__device__ __forceinline__ void gload16(const u16* g, u16* l) {
  __builtin_amdgcn_global_load_lds(
      (const __attribute__((address_space(1))) unsigned int*)g,
      (__attribute__((address_space(3))) unsigned int*)l, 16, 0, 0);
}

__global__ __launch_bounds__(256) void fill_sentinel(u16* out, int n) {
  int i = blockIdx.x * 256 + threadIdx.x;
  if (i < n) out[i] = 0x42DE;  // bf16 111.0
}

// ---------------- dtype detect ----------------
__global__ __launch_bounds__(256) void detect_dtype(const u16* __restrict__ x, int* flag) {
  __shared__ int cnt;
  if (threadIdx.x == 0) cnt = 0;
  __syncthreads();
  int c = 0;
  for (int i = threadIdx.x; i < 8192; i += 256) {
    const unsigned e = (x[i] >> 7) & 0xFFu;
    if (e >= 0xC0u) ++c;
  }
  atomicAdd(&cnt, c);
  __syncthreads();
  if (threadIdx.x == 0) *flag = (cnt > 64) ? 1 : 0;  // 1 = fp32 inputs
}

// ---------------- input conversion ----------------
__global__ __launch_bounds__(256) void convert_in(const void* __restrict__ src,
                                                  u16* __restrict__ dst, int n,
                                                  const int* __restrict__ flag) {
  const int i = blockIdx.x * 256 + threadIdx.x;
  if (i >= n) return;
  if (*flag) dst[i] = f2b(((const float*)src)[i]);
  else dst[i] = ((const u16*)src)[i];
}

// ---------------- weight transpose + convert ----------------
__global__ __launch_bounds__(256) void transpose_cv(const void* __restrict__ in,
                                                    u16* __restrict__ out, int R, int C,
                                                    const int* __restrict__ flag) {
  __shared__ u16 t[32][33];
  const int f32 = *flag;
  const int bc = blockIdx.x * 32, br = blockIdx.y * 32;
  const int tx = threadIdx.x & 31, ty = threadIdx.x >> 5;
  for (int i = ty; i < 32; i += 8) {
    const size_t idx = (size_t)(br + i) * C + bc + tx;
    t[i][tx] = f32 ? f2b(((const float*)in)[idx]) : ((const u16*)in)[idx];
  }
  __syncthreads();
  for (int i = ty; i < 32; i += 8) out[(size_t)(bc + i) * R + br + tx] = t[tx][i];
}

// ---------------- GEMM v3: XOR-swizzled LDS + cross-buffer prefetch ----------------
enum { F_BIAS = 1, F_RELU = 2, F_RES = 4, F_QKV = 8 };

// LDS: row-major [TM+TN rows][32 u16], k-chunk q (16B) of row r at slot q^((r>>1)&3).
// Global: 4 consecutive lanes = one row's contiguous 64B (permuted within line).
// Frag reads: banks 16(lm&1)+4(quad^((lm>>1)&3)) -> 2-way (free).
template <int TM, int TN, int WM, int WN, int FLAGS>
__global__ __launch_bounds__(256) void gemm3(
    const u16* __restrict__ A, const u16* __restrict__ Bt,
    u16* __restrict__ out0, u16* __restrict__ out1,
    u16* __restrict__ out2, u16* __restrict__ out3,
    const u16* __restrict__ bias0, const u16* __restrict__ bias1,
    const u16* __restrict__ res, int M, int N, int K) {
  constexpr int WAVES_M = TM / WM;
  constexpr int MT = WM / 16, NT = WN / 16;
  constexpr int NI = (TM + TN) / 64;  // issues per wave per k-step
  static_assert((TM / WM) * (TN / WN) == 4, "4 waves");
  __shared__ u16 SM[2][(TM + TN) * 32];

  const int m0 = blockIdx.y * TM;
  const int n0 = blockIdx.x * TN;
  const int tid = threadIdx.x;
  const int wid = tid >> 6, lane = tid & 63;
  const int wm = (wid % WAVES_M) * WM, wn = (wid / WAVES_M) * WN;
  const int lm = lane & 15, quad = lane >> 4;

  floatx4 acc[MT][NT];
#pragma unroll
  for (int i = 0; i < MT; ++i)
#pragma unroll
    for (int j = 0; j < NT; ++j) acc[i][j] = (floatx4){0.f, 0.f, 0.f, 0.f};

  // staging: issue j covers rows 16j..16j+15; lane l -> row 16j+(l>>2), slot l&3
  const u16* srcs[NI];  // per-lane global base (advance by 32 u16 / step)
  int ldso[NI];         // wave-uniform LDS u16 offset of issue j
#pragma unroll
  for (int i = 0; i < NI; ++i) {
    const int j = wid + 4 * i;
    const int r = j * 16 + (lane >> 2);
    const int q = (lane & 3) ^ ((r >> 1) & 3);  // global k-chunk at this lane's slot
    const u16* p;
    if (r < TM) {
      int ga = m0 + r;
      if (ga > M - 1) ga = M - 1;  // clamp; epilogue guards
      p = A + (size_t)ga * K + q * 8;
    } else {
      p = Bt + (size_t)(n0 + r - TM) * K + q * 8;
    }
    srcs[i] = p;
    ldso[i] = j * 512;
  }
  const int slot = (quad ^ ((lm >> 1) & 3)) * 8;
  int aoff[MT], boff[NT];
#pragma unroll
  for (int t = 0; t < MT; ++t) aoff[t] = (wm + t * 16 + lm) * 32 + slot;
#pragma unroll
  for (int t = 0; t < NT; ++t) boff[t] = (TM + wn + t * 16 + lm) * 32 + slot;

  // preload k=0 into buf 0
#pragma unroll
  for (int i = 0; i < NI; ++i) gload16(srcs[i], &SM[0][ldso[i]]);
  __syncthreads();

  int buf = 0;
  for (int k0 = 0; k0 < K; k0 += 32, buf ^= 1) {
    if (k0 + 32 < K) {
      const int koff = (k0 + 32);
#pragma unroll
      for (int i = 0; i < NI; ++i) gload16(srcs[i] + koff, &SM[buf ^ 1][ldso[i]]);
    }
    short8 af[MT], bf[NT];
#pragma unroll
    for (int t = 0; t < MT; ++t) af[t] = *(const short8*)(&SM[buf][aoff[t]]);
#pragma unroll
    for (int t = 0; t < NT; ++t) bf[t] = *(const short8*)(&SM[buf][boff[t]]);
#pragma unroll
    for (int tm = 0; tm < MT; ++tm)
#pragma unroll
      for (int tn = 0; tn < NT; ++tn)
        acc[tm][tn] = __builtin_amdgcn_mfma_f32_16x16x32_bf16(af[tm], bf[tn], acc[tm][tn], 0, 0, 0);
    __syncthreads();  // drains prefetch (post-compute) + protects buffer reuse
  }

#pragma unroll
  for (int tm = 0; tm < MT; ++tm) {
#pragma unroll
    for (int tn = 0; tn < NT; ++tn) {
      const int gcol = n0 + wn + tn * 16 + lm;
#pragma unroll
      for (int r = 0; r < 4; ++r) {
        const int grow = m0 + wm + tm * 16 + quad * 4 + r;
        if (grow >= M) continue;
        float val = acc[tm][tn][r];
        if (FLAGS & F_QKV) {
          const int region = gcol / 768;  // block-uniform (TN | 768)
          const int c = gcol - region * 768;
          if (region == 0) {
            out0[(size_t)grow * 768 + c] = f2b(val + b2f(bias0[c]));  // q + u
            out1[(size_t)grow * 768 + c] = f2b(val + b2f(bias1[c]));  // q + v
          } else if (region == 1) {
            out2[(size_t)grow * 768 + c] = f2b(val);                  // k
          } else {
            const int bb = grow / S_, s = grow - bb * S_;
            out3[((size_t)bb * D_ + c) * S_ + s] = f2b(val);          // v transposed
          }
        } else {
          if (FLAGS & F_BIAS) val += b2f(bias0[gcol]);
          if (FLAGS & F_RES) val += b2f(res[(size_t)grow * N + gcol]);
          if (FLAGS & F_RELU) val = fmaxf(val, 0.f);
          out0[(size_t)grow * N + gcol] = f2b(val);
        }
      }
    }
  }
}

// ---------------- fused rel-pos attention (unchanged, verified) ----------------
__global__ __launch_bounds__(256) void attn_kernel(
    const u16* __restrict__ qu, const u16* __restrict__ qv,
    const u16* __restrict__ kb, const u16* __restrict__ vt,
    const u16* __restrict__ rb, u16* __restrict__ attn) {
  __shared__ float sc[16][384];
  __shared__ u16 p[16][392];
  __shared__ float red[16][16];
  __shared__ float rmax[16], rsum[16];

  const int qt = blockIdx.x, bh = blockIdx.y;
  const int b = bh / H_, h = bh % H_;
  const int i0 = qt * 16;
  const int tid = threadIdx.x, wid = tid >> 6, lane = tid & 63;
  const int lm = lane & 15, quad = lane >> 4;
  float* scf = &sc[0][0];

  for (int i = tid; i < 16 * 384; i += 256) scf[i] = 0.f;
  __syncthreads();

  const size_t qrow = ((size_t)(b * S_ + i0 + lm)) * D_ + h * DH_;
  {
    const short8 a0 = *(const short8*)(qv + qrow + quad * 8);
    const short8 a1 = *(const short8*)(qv + qrow + 32 + quad * 8);
    for (int tt = wid; tt < 25; tt += 4) {
      const int trel = tt * 16 + lm;
      int t = i0 + trel;
      if (t > 766) t = 766;
      const size_t rrow = (size_t)t * D_ + h * DH_;
      const short8 b0 = *(const short8*)(rb + rrow + quad * 8);
      const short8 b1 = *(const short8*)(rb + rrow + 32 + quad * 8);
      floatx4 e = (floatx4){0.f, 0.f, 0.f, 0.f};
      e = __builtin_amdgcn_mfma_f32_16x16x32_bf16(a0, b0, e, 0, 0, 0);
      e = __builtin_amdgcn_mfma_f32_16x16x32_bf16(a1, b1, e, 0, 0, 0);
#pragma unroll
      for (int r = 0; r < 4; ++r) {
        const int row = quad * 4 + r;
        const int j = row - trel + 383;
        if (j >= 0 && j < 384) sc[row][j] += e[r];
      }
    }
  }
  __syncthreads();
  {
    const short8 a0 = *(const short8*)(qu + qrow + quad * 8);
    const short8 a1 = *(const short8*)(qu + qrow + 32 + quad * 8);
    for (int q = 0; q < 6; ++q) {
      const int j0 = (wid * 6 + q) * 16;
      const size_t krow = ((size_t)(b * S_ + j0 + lm)) * D_ + h * DH_;
      const short8 b0 = *(const short8*)(kb + krow + quad * 8);
      const short8 b1 = *(const short8*)(kb + krow + 32 + quad * 8);
      floatx4 e = (floatx4){0.f, 0.f, 0.f, 0.f};
      e = __builtin_amdgcn_mfma_f32_16x16x32_bf16(a0, b0, e, 0, 0, 0);
      e = __builtin_amdgcn_mfma_f32_16x16x32_bf16(a1, b1, e, 0, 0, 0);
#pragma unroll
      for (int r = 0; r < 4; ++r) {
        const int row = quad * 4 + r;
        sc[row][j0 + lm] = (sc[row][j0 + lm] + e[r]) * 0.125f;
      }
    }
  }
  __syncthreads();
  {
    const int row = tid >> 4, sub = tid & 15;
    float lmax = -1e30f;
    for (int cc = 0; cc < 24; ++cc) lmax = fmaxf(lmax, sc[row][sub + cc * 16]);
    red[row][sub] = lmax;
    __syncthreads();
    if (sub == 0) {
      float m = red[row][0];
      for (int i = 1; i < 16; ++i) m = fmaxf(m, red[row][i]);
      rmax[row] = m;
    }
    __syncthreads();
    const float m = rmax[row];
    float lsum = 0.f;
    for (int cc = 0; cc < 24; ++cc) {
      const int c = sub + cc * 16;
      const float e = __expf(sc[row][c] - m);
      p[row][c] = f2b(e);
      lsum += e;
    }
    red[row][sub] = lsum;
    __syncthreads();
    if (sub == 0) {
      float s2 = 0.f;
      for (int i = 0; i < 16; ++i) s2 += red[row][i];
      rsum[row] = s2;
    }
    __syncthreads();
  }
  floatx4 o[4];
#pragma unroll
  for (int nt = 0; nt < 4; ++nt) o[nt] = (floatx4){0.f, 0.f, 0.f, 0.f};
  for (int kk = 0; kk < 3; ++kk) {
    const int kbase = wid * 96 + kk * 32;
    const short8 af = *(const short8*)(&p[lm][kbase + quad * 8]);
#pragma unroll
    for (int nt = 0; nt < 4; ++nt) {
      const size_t vrow = ((size_t)(b * D_ + h * DH_ + nt * 16 + lm)) * S_;
      const short8 bv = *(const short8*)(vt + vrow + kbase + quad * 8);
      o[nt] = __builtin_amdgcn_mfma_f32_16x16x32_bf16(af, bv, o[nt], 0, 0, 0);
    }
  }
  __syncthreads();
#pragma unroll
  for (int nt = 0; nt < 4; ++nt)
#pragma unroll
    for (int r = 0; r < 4; ++r) {
      const int row = quad * 4 + r, dh = nt * 16 + lm;
      scf[wid * 1024 + row * 64 + dh] = o[nt][r];
    }
  __syncthreads();
  for (int t = tid; t < 1024; t += 256) {
    const int row = t >> 6, dh = t & 63;
    float v = scf[row * 64 + dh] + scf[1024 + row * 64 + dh] +
              scf[2048 + row * 64 + dh] + scf[3072 + row * 64 + dh];
    v /= rsum[row];
    attn[((size_t)(b * S_ + i0 + row)) * D_ + h * DH_ + dh] = f2b(v);
  }
}

// ---------------- row layernorm ----------------
__global__ __launch_bounds__(256) void ln_kernel(const u16* __restrict__ y,
                                                 const u16* __restrict__ g,
                                                 const u16* __restrict__ bb,
                                                 void* __restrict__ outv,
                                                 const int* __restrict__ flag, int dual) {
  const int row = blockIdx.x * 4 + (threadIdx.x >> 6);
  const int lane = threadIdx.x & 63;
  const u16* yr = y + (size_t)row * D_;
  float vbuf[12], s = 0.f, s2 = 0.f;
#pragma unroll
  for (int i = 0; i < 12; ++i) {
    const float x = b2f(yr[lane + i * 64]);
    vbuf[i] = x;
    s += x;
    s2 += x * x;
  }
#pragma unroll
  for (int off = 32; off; off >>= 1) {
    s += __shfl_down(s, off);
    s2 += __shfl_down(s2, off);
  }
  s = __shfl(s, 0);
  s2 = __shfl(s2, 0);
  const float mean = s * (1.f / 768.f);
  const float var = s2 * (1.f / 768.f) - mean * mean;
  const float inv = rsqrtf(var + 1e-5f);
  const int f32out = dual && *flag;
#pragma unroll
  for (int i = 0; i < 12; ++i) {
    const int c = lane + i * 64;
    const float val = (vbuf[i] - mean) * inv * b2f(g[c]) + b2f(bb[c]);
    if (f32out) ((float*)outv)[(size_t)row * D_ + c] = val;
    else ((u16*)outv)[(size_t)row * D_ + c] = f2b(val);
  }
}

// ---------------- host ----------------
extern "C" void kernel_launch(void* const* d_in, const int* in_sizes, int n_in,
                              void* d_out, int out_size, void* d_ws, size_t ws_size,
                              hipStream_t stream) {
  const void* x    = d_in[0];
  const void* pe   = d_in[1];
  const void* Wq   = d_in[2];
  const void* Wk   = d_in[3];
  const void* Wv   = d_in[4];
  const void* Wr   = d_in[5];
  const void* ub   = d_in[6];
  const void* vb   = d_in[7];
  const void* Wo   = d_in[8];
  const void* ln1g = d_in[9];
  const void* ln1b = d_in[10];
  const void* ln2g = d_in[11];
  const void* ln2b = d_in[12];
  const void* W1   = d_in[13];
  const void* b1   = d_in[14];
  const void* W2   = d_in[15];
  const void* b2   = d_in[16];
  char* ws = (char*)d_ws;

  constexpr int N_X  = B_ * S_ * D_;
  constexpr int N_PE = (2 * S_ - 1) * D_;

  constexpr size_t O_W   = 0;
  constexpr size_t O_SM  = 15335424;
  constexpr size_t O_XB  = 15368192;
  constexpr size_t O_QU  = 24805376;
  constexpr size_t O_QV  = 34242560;
  constexpr size_t O_KB  = 43679744;
  constexpr size_t O_VT  = 53116928;
  constexpr size_t O_RB  = 62554112;
  constexpr size_t NEEDED = 63733760;

  if (ws_size < NEEDED) {
    fill_sentinel<<<(out_size + 255) / 256, 256, 0, stream>>>((u16*)d_out, out_size);
    return;
  }

  int* flag = (int*)(ws + O_SM);
  u16* ubc  = (u16*)(ws + O_SM + 128);
  u16* vbc  = (u16*)(ws + O_SM + 1664);
  u16* b1c  = (u16*)(ws + O_SM + 3200);
  u16* b2c  = (u16*)(ws + O_SM + 9344);
  u16* g1c  = (u16*)(ws + O_SM + 10880);
  u16* be1c = (u16*)(ws + O_SM + 12416);
  u16* g2c  = (u16*)(ws + O_SM + 13952);
  u16* be2c = (u16*)(ws + O_SM + 15488);

  u16* wtq = (u16*)(ws + O_W);   // wtq|wtk|wtv contiguous => fused QKV B (N=2304)
  u16* wtk = wtq + (size_t)D_ * D_;
  u16* wtv = wtk + (size_t)D_ * D_;
  u16* wtr = wtv + (size_t)D_ * D_;
  u16* wto = wtr + (size_t)D_ * D_;
  u16* wt1 = wto + (size_t)D_ * D_;
  u16* wt2 = wt1 + (size_t)D_ * FF_;

  u16* xb  = (u16*)(ws + O_XB);
  u16* quB = (u16*)(ws + O_QU);
  u16* peb = (u16*)(ws + O_QV);
  u16* qvB = (u16*)(ws + O_QV);
  u16* kbB = (u16*)(ws + O_KB);
  u16* vtB = (u16*)(ws + O_VT);
  u16* rbB = (u16*)(ws + O_RB);
  u16* atB = (u16*)d_out;
  u16* y1B = xb;
  u16* x1B = (u16*)(ws + O_VT);
  u16* ffB = xb;
  u16* y2B = x1B;

  detect_dtype<<<1, 256, 0, stream>>>((const u16*)x, flag);
  convert_in<<<(N_X + 255) / 256, 256, 0, stream>>>(x, xb, N_X, flag);
  convert_in<<<(N_PE + 255) / 256, 256, 0, stream>>>(pe, peb, N_PE, flag);
  convert_in<<<3, 256, 0, stream>>>(ub, ubc, 768, flag);
  convert_in<<<3, 256, 0, stream>>>(vb, vbc, 768, flag);
  convert_in<<<12, 256, 0, stream>>>(b1, b1c, 3072, flag);
  convert_in<<<3, 256, 0, stream>>>(b2, b2c, 768, flag);
  convert_in<<<3, 256, 0, stream>>>(ln1g, g1c, 768, flag);
  convert_in<<<3, 256, 0, stream>>>(ln1b, be1c, 768, flag);
  convert_in<<<3, 256, 0, stream>>>(ln2g, g2c, 768, flag);
  convert_in<<<3, 256, 0, stream>>>(ln2b, be2c, 768, flag);
  transpose_cv<<<dim3(24, 24), 256, 0, stream>>>(Wq, wtq, D_, D_, flag);
  transpose_cv<<<dim3(24, 24), 256, 0, stream>>>(Wk, wtk, D_, D_, flag);
  transpose_cv<<<dim3(24, 24), 256, 0, stream>>>(Wv, wtv, D_, D_, flag);
  transpose_cv<<<dim3(24, 24), 256, 0, stream>>>(Wr, wtr, D_, D_, flag);
  transpose_cv<<<dim3(24, 24), 256, 0, stream>>>(Wo, wto, D_, D_, flag);
  transpose_cv<<<dim3(96, 24), 256, 0, stream>>>(W1, wt1, D_, FF_, flag);
  transpose_cv<<<dim3(24, 96), 256, 0, stream>>>(W2, wt2, FF_, D_, flag);

  // r-proj: M=767 -> 64x64 tiles, grid 144
  gemm3<64, 64, 32, 32, 0><<<dim3(12, 12), 256, 0, stream>>>(
      peb, wtr, rbB, nullptr, nullptr, nullptr, nullptr, nullptr, nullptr,
      2 * S_ - 1, D_, D_);
  // fused QKV: N=2304, 128x128 -> 864 blocks
  gemm3<128, 128, 64, 64, F_QKV><<<dim3(18, 48), 256, 0, stream>>>(
      xb, wtq, quB, qvB, kbB, vtB, ubc, vbc, nullptr, B_ * S_, 2304, D_);
  // attention -> d_out scratch
  attn_kernel<<<dim3(S_ / 16, B_ * H_), 256, 0, stream>>>(quB, qvB, kbB, vtB, rbB, atB);
  // Wo + residual: 64x128 -> 576 blocks (A re-read 6x)
  gemm3<64, 128, 32, 64, F_RES><<<dim3(6, 96), 256, 0, stream>>>(
      atB, wto, y1B, nullptr, nullptr, nullptr, nullptr, nullptr, xb, B_ * S_, D_, D_);
  ln_kernel<<<B_ * S_ / 4, 256, 0, stream>>>(y1B, g1c, be1c, x1B, flag, 0);
  // FFN1: 128x128 -> 1152 blocks
  gemm3<128, 128, 64, 64, F_BIAS | F_RELU><<<dim3(24, 48), 256, 0, stream>>>(
      x1B, wt1, ffB, nullptr, nullptr, nullptr, b1c, nullptr, nullptr, B_ * S_, FF_, D_);
  // FFN2: K=3072, 64x128 -> 576 blocks
  gemm3<64, 128, 32, 64, F_BIAS | F_RES><<<dim3(6, 96), 256, 0, stream>>>(
      ffB, wt2, y2B, nullptr, nullptr, nullptr, b2c, nullptr, x1B, B_ * S_, D_, FF_);
  ln_kernel<<<B_ * S_ / 4, 256, 0, stream>>>(y2B, g2c, be2c, d_out, flag, 1);
}

// Round 6
// 466.286 us; speedup vs baseline: 1.3437x; 1.0802x over previous
//
#include <hip/hip_runtime.h>

typedef unsigned short u16;
typedef __attribute__((ext_vector_type(8))) short short8;
typedef __attribute__((ext_vector_type(4))) float floatx4;

#define B_  16
#define S_  384
#define D_  768
#define H_  12
#define DH_ 64
#define FF_ 3072

__device__ __forceinline__ float b2f(u16 h) { return __uint_as_float(((unsigned)h) << 16); }
__device__ __forceinline__ u16 f2b(float f) {
  unsigned u = __float_as_uint(f);
  u += 0x7fffu + ((u >> 16) & 1u);
  return (u16)(u >> 16);
}

__device__ __forceinline__ void gload16(const u16* g, u16* l) {
  __builtin_amdgcn_global_load_lds(
      (const __attribute__((address_space(1))) unsigned int*)g,
      (__attribute__((address_space(3))) unsigned int*)l, 16, 0, 0);
}

__global__ __launch_bounds__(256) void fill_sentinel(u16* out, int n) {
  int i = blockIdx.x * 256 + threadIdx.x;
  if (i < n) out[i] = 0x42DE;  // bf16 111.0
}

// ---------------- dtype detect ----------------
__global__ __launch_bounds__(256) void detect_dtype(const u16* __restrict__ x, int* flag) {
  __shared__ int cnt;
  if (threadIdx.x == 0) cnt = 0;
  __syncthreads();
  int c = 0;
  for (int i = threadIdx.x; i < 8192; i += 256) {
    const unsigned e = (x[i] >> 7) & 0xFFu;
    if (e >= 0xC0u) ++c;
  }
  atomicAdd(&cnt, c);
  __syncthreads();
  if (threadIdx.x == 0) *flag = (cnt > 64) ? 1 : 0;  // 1 = fp32 inputs
}

// ---------------- x/pe conversion, 4-wide ----------------
__global__ __launch_bounds__(256) void convert_in4(const void* __restrict__ src,
                                                   u16* __restrict__ dst, int n4,
                                                   const int* __restrict__ flag) {
  const int i = blockIdx.x * 256 + threadIdx.x;
  if (i >= n4) return;
  if (*flag) {
    const float4 f = ((const float4*)src)[i];
    ushort4 o;
    o.x = f2b(f.x); o.y = f2b(f.y); o.z = f2b(f.z); o.w = f2b(f.w);
    ((ushort4*)dst)[i] = o;
  } else {
    ((ushort4*)dst)[i] = ((const ushort4*)src)[i];
  }
}

// ---------------- all small tensors in one launch (8448 elems) ----------------
__global__ __launch_bounds__(256) void convert_small(
    const void* b1, const void* ub, const void* vb, const void* b2,
    const void* g1, const void* be1, const void* g2, const void* be2,
    u16* b1c, u16* ubc, u16* vbc, u16* b2c,
    u16* g1c, u16* be1c, u16* g2c, u16* be2c, const int* __restrict__ flag) {
  const int i = blockIdx.x * 256 + threadIdx.x;
  if (i >= 8448) return;
  const void* s; u16* d; int off;
  if (i < 3072) { s = b1; d = b1c; off = i; }
  else {
    const int r = i - 3072, sg = r / 768; off = r - sg * 768;
    switch (sg) {
      case 0: s = ub;  d = ubc;  break;
      case 1: s = vb;  d = vbc;  break;
      case 2: s = b2;  d = b2c;  break;
      case 3: s = g1;  d = g1c;  break;
      case 4: s = be1; d = be1c; break;
      case 5: s = g2;  d = g2c;  break;
      default: s = be2; d = be2c; break;
    }
  }
  d[off] = (*flag) ? f2b(((const float*)s)[off]) : ((const u16*)s)[off];
}

// ---------------- all 7 weight transposes in one launch ----------------
struct TP { const void* src[7]; u16* dst[7]; };
__global__ __launch_bounds__(256) void transpose_all(TP tp, const int* __restrict__ flag) {
  __shared__ u16 t[32][33];
  const int f32 = *flag;
  const int id = blockIdx.x;
  int w, tt, R, C, bc, br;
  if (id < 2880)      { w = id / 576; tt = id % 576;  R = 768;  C = 768;  bc = (tt % 24) * 32; br = (tt / 24) * 32; }
  else if (id < 5184) { w = 5;        tt = id - 2880; R = 768;  C = 3072; bc = (tt % 96) * 32; br = (tt / 96) * 32; }
  else                { w = 6;        tt = id - 5184; R = 3072; C = 768;  bc = (tt % 24) * 32; br = (tt / 24) * 32; }
  const void* in = tp.src[w];
  u16* out = tp.dst[w];
  const int tx = threadIdx.x & 31, ty = threadIdx.x >> 5;
  for (int i = ty; i < 32; i += 8) {
    const size_t idx = (size_t)(br + i) * C + bc + tx;
    t[i][tx] = f32 ? f2b(((const float*)in)[idx]) : ((const u16*)in)[idx];
  }
  __syncthreads();
  for (int i = ty; i < 32; i += 8) out[(size_t)(bc + i) * R + br + tx] = t[tx][i];
}

// ---------------- GEMM v3 (verified r5): XOR-swizzled LDS + prefetch ----------------
enum { F_BIAS = 1, F_RELU = 2, F_RES = 4, F_QKV = 8 };

template <int TM, int TN, int WM, int WN, int FLAGS>
__global__ __launch_bounds__(256) void gemm3(
    const u16* __restrict__ A, const u16* __restrict__ Bt,
    u16* __restrict__ out0, u16* __restrict__ out1,
    u16* __restrict__ out2, u16* __restrict__ out3,
    const u16* __restrict__ bias0, const u16* __restrict__ bias1,
    const u16* __restrict__ res, int M, int N, int K) {
  constexpr int WAVES_M = TM / WM;
  constexpr int MT = WM / 16, NT = WN / 16;
  constexpr int NI = (TM + TN) / 64;
  static_assert((TM / WM) * (TN / WN) == 4, "4 waves");
  __shared__ u16 SM[2][(TM + TN) * 32];

  const int m0 = blockIdx.y * TM;
  const int n0 = blockIdx.x * TN;
  const int tid = threadIdx.x;
  const int wid = tid >> 6, lane = tid & 63;
  const int wm = (wid % WAVES_M) * WM, wn = (wid / WAVES_M) * WN;
  const int lm = lane & 15, quad = lane >> 4;

  floatx4 acc[MT][NT];
#pragma unroll
  for (int i = 0; i < MT; ++i)
#pragma unroll
    for (int j = 0; j < NT; ++j) acc[i][j] = (floatx4){0.f, 0.f, 0.f, 0.f};

  const u16* srcs[NI];
  int ldso[NI];
#pragma unroll
  for (int i = 0; i < NI; ++i) {
    const int j = wid + 4 * i;
    const int r = j * 16 + (lane >> 2);
    const int q = (lane & 3) ^ ((r >> 1) & 3);
    const u16* p;
    if (r < TM) {
      int ga = m0 + r;
      if (ga > M - 1) ga = M - 1;
      p = A + (size_t)ga * K + q * 8;
    } else {
      p = Bt + (size_t)(n0 + r - TM) * K + q * 8;
    }
    srcs[i] = p;
    ldso[i] = j * 512;
  }
  const int slot = (quad ^ ((lm >> 1) & 3)) * 8;
  int aoff[MT], boff[NT];
#pragma unroll
  for (int t = 0; t < MT; ++t) aoff[t] = (wm + t * 16 + lm) * 32 + slot;
#pragma unroll
  for (int t = 0; t < NT; ++t) boff[t] = (TM + wn + t * 16 + lm) * 32 + slot;

#pragma unroll
  for (int i = 0; i < NI; ++i) gload16(srcs[i], &SM[0][ldso[i]]);
  __syncthreads();

  int buf = 0;
  for (int k0 = 0; k0 < K; k0 += 32, buf ^= 1) {
    if (k0 + 32 < K) {
      const int koff = (k0 + 32);
#pragma unroll
      for (int i = 0; i < NI; ++i) gload16(srcs[i] + koff, &SM[buf ^ 1][ldso[i]]);
    }
    short8 af[MT], bf[NT];
#pragma unroll
    for (int t = 0; t < MT; ++t) af[t] = *(const short8*)(&SM[buf][aoff[t]]);
#pragma unroll
    for (int t = 0; t < NT; ++t) bf[t] = *(const short8*)(&SM[buf][boff[t]]);
#pragma unroll
    for (int tm = 0; tm < MT; ++tm)
#pragma unroll
      for (int tn = 0; tn < NT; ++tn)
        acc[tm][tn] = __builtin_amdgcn_mfma_f32_16x16x32_bf16(af[tm], bf[tn], acc[tm][tn], 0, 0, 0);
    __syncthreads();
  }

#pragma unroll
  for (int tm = 0; tm < MT; ++tm) {
#pragma unroll
    for (int tn = 0; tn < NT; ++tn) {
      const int gcol = n0 + wn + tn * 16 + lm;
#pragma unroll
      for (int r = 0; r < 4; ++r) {
        const int grow = m0 + wm + tm * 16 + quad * 4 + r;
        if (grow >= M) continue;
        float val = acc[tm][tn][r];
        if (FLAGS & F_QKV) {
          const int region = gcol / 768;
          const int c = gcol - region * 768;
          if (region == 0) {
            out0[(size_t)grow * 768 + c] = f2b(val + b2f(bias0[c]));
            out1[(size_t)grow * 768 + c] = f2b(val + b2f(bias1[c]));
          } else if (region == 1) {
            out2[(size_t)grow * 768 + c] = f2b(val);
          } else {
            const int bb = grow / S_, s = grow - bb * S_;
            out3[((size_t)bb * D_ + c) * S_ + s] = f2b(val);
          }
        } else {
          if (FLAGS & F_BIAS) val += b2f(bias0[gcol]);
          if (FLAGS & F_RES) val += b2f(res[(size_t)grow * N + gcol]);
          if (FLAGS & F_RELU) val = fmaxf(val, 0.f);
          out0[(size_t)grow * N + gcol] = f2b(val);
        }
      }
    }
  }
}

// ---------------- attention v2: dense-E, shuffle softmax, 3 barriers ----------------
// grid: 4608 linear, swizzled so all 24 q-tiles of a (b,h) share id%8 (same XCD).
__global__ __launch_bounds__(256) void attn_kernel(
    const u16* __restrict__ qu, const u16* __restrict__ qv,
    const u16* __restrict__ kb, const u16* __restrict__ vt,
    const u16* __restrict__ rb, u16* __restrict__ attn) {
  __shared__ float scA[16 * 388];   // A_C scores; later overlaid by P (row-aligned)
  __shared__ float E[16 * 404];     // B_D dense; later overlaid by PV partials
  __shared__ float rsum[16];

  const int id = blockIdx.x;
  const int g = id >> 3;
  const int qt = g % 24;
  const int bh = (id & 7) + 8 * (g / 24);
  const int b = bh / H_, h = bh % H_;
  const int i0 = qt * 16;
  const int tid = threadIdx.x, wid = tid >> 6, lane = tid & 63;
  const int lm = lane & 15, quad = lane >> 4;

  const size_t qrow = ((size_t)(b * S_ + i0 + lm)) * D_ + h * DH_;
  // ---- B_D: E[row][trel] = (q_row+v)·r[i0+trel], dense stores, no init ----
  {
    const short8 a0 = *(const short8*)(qv + qrow + quad * 8);
    const short8 a1 = *(const short8*)(qv + qrow + 32 + quad * 8);
    for (int tt = wid; tt < 25; tt += 4) {
      const int trel = tt * 16 + lm;
      int t = i0 + trel;
      if (t > 766) t = 766;  // load clamp; trel=399 never gathered
      const size_t rrow = (size_t)t * D_ + h * DH_;
      const short8 b0 = *(const short8*)(rb + rrow + quad * 8);
      const short8 b1 = *(const short8*)(rb + rrow + 32 + quad * 8);
      floatx4 e = (floatx4){0.f, 0.f, 0.f, 0.f};
      e = __builtin_amdgcn_mfma_f32_16x16x32_bf16(a0, b0, e, 0, 0, 0);
      e = __builtin_amdgcn_mfma_f32_16x16x32_bf16(a1, b1, e, 0, 0, 0);
#pragma unroll
      for (int r = 0; r < 4; ++r) E[(quad * 4 + r) * 404 + trel] = e[r];
    }
  }
  // ---- A_C: direct stores (scale folded into softmax) ----
  {
    const short8 a0 = *(const short8*)(qu + qrow + quad * 8);
    const short8 a1 = *(const short8*)(qu + qrow + 32 + quad * 8);
    for (int q = 0; q < 6; ++q) {
      const int j0 = (wid * 6 + q) * 16;
      const size_t krow = ((size_t)(b * S_ + j0 + lm)) * D_ + h * DH_;
      const short8 b0 = *(const short8*)(kb + krow + quad * 8);
      const short8 b1 = *(const short8*)(kb + krow + 32 + quad * 8);
      floatx4 e = (floatx4){0.f, 0.f, 0.f, 0.f};
      e = __builtin_amdgcn_mfma_f32_16x16x32_bf16(a0, b0, e, 0, 0, 0);
      e = __builtin_amdgcn_mfma_f32_16x16x32_bf16(a1, b1, e, 0, 0, 0);
#pragma unroll
      for (int r = 0; r < 4; ++r) scA[(quad * 4 + r) * 388 + j0 + lm] = e[r];
    }
  }
  __syncthreads();  // barrier 1

  // ---- softmax: row = wid*4+quad, cols lm+16cc; in-wave shuffle reductions ----
  u16* p16 = (u16*)scA;  // P[row][c] at u16 idx row*776 + c (inside scA row r's slab)
  {
    const int row = wid * 4 + quad;
    float v[24];
    float lmax = -1e30f;
#pragma unroll
    for (int cc = 0; cc < 24; ++cc) {
      const int c = lm + cc * 16;
      const float s = (scA[row * 388 + c] + E[row * 404 + row + 383 - c]) * 0.125f;
      v[cc] = s;
      lmax = fmaxf(lmax, s);
    }
#pragma unroll
    for (int m = 1; m < 16; m <<= 1) lmax = fmaxf(lmax, __shfl_xor(lmax, m));
    float lsum = 0.f;
#pragma unroll
    for (int cc = 0; cc < 24; ++cc) {
      const float e = __expf(v[cc] - lmax);
      p16[row * 776 + lm + cc * 16] = f2b(e);
      lsum += e;
    }
#pragma unroll
    for (int m = 1; m < 16; m <<= 1) lsum += __shfl_xor(lsum, m);
    if (lm == 0) rsum[row] = lsum;
  }
  __syncthreads();  // barrier 2

  // ---- PV: wave w owns keys [w*96, w*96+96); partials into dead E region ----
  floatx4 o[4];
#pragma unroll
  for (int nt = 0; nt < 4; ++nt) o[nt] = (floatx4){0.f, 0.f, 0.f, 0.f};
  for (int kk = 0; kk < 3; ++kk) {
    const int kbase = wid * 96 + kk * 32;
    const short8 af = *(const short8*)(&p16[lm * 776 + kbase + quad * 8]);
#pragma unroll
    for (int nt = 0; nt < 4; ++nt) {
      const size_t vrow = ((size_t)(b * D_ + h * DH_ + nt * 16 + lm)) * S_;
      const short8 bv = *(const short8*)(vt + vrow + kbase + quad * 8);
      o[nt] = __builtin_amdgcn_mfma_f32_16x16x32_bf16(af, bv, o[nt], 0, 0, 0);
    }
  }
#pragma unroll
  for (int nt = 0; nt < 4; ++nt)
#pragma unroll
    for (int r = 0; r < 4; ++r)
      E[wid * 1088 + (quad * 4 + r) * 68 + nt * 16 + lm] = o[nt][r];
  __syncthreads();  // barrier 3

#pragma unroll
  for (int i = 0; i < 4; ++i) {
    const int idx = tid + 256 * i;
    const int row = idx >> 6, dh = idx & 63;
    float v = E[row * 68 + dh] + E[1088 + row * 68 + dh] +
              E[2176 + row * 68 + dh] + E[3264 + row * 68 + dh];
    v /= rsum[row];
    attn[((size_t)(b * S_ + i0 + row)) * D_ + h * DH_ + dh] = f2b(v);
  }
}

// ---------------- row layernorm ----------------
__global__ __launch_bounds__(256) void ln_kernel(const u16* __restrict__ y,
                                                 const u16* __restrict__ g,
                                                 const u16* __restrict__ bb,
                                                 void* __restrict__ outv,
                                                 const int* __restrict__ flag, int dual) {
  const int row = blockIdx.x * 4 + (threadIdx.x >> 6);
  const int lane = threadIdx.x & 63;
  const u16* yr = y + (size_t)row * D_;
  float vbuf[12], s = 0.f, s2 = 0.f;
#pragma unroll
  for (int i = 0; i < 12; ++i) {
    const float x = b2f(yr[lane + i * 64]);
    vbuf[i] = x;
    s += x;
    s2 += x * x;
  }
#pragma unroll
  for (int off = 32; off; off >>= 1) {
    s += __shfl_down(s, off);
    s2 += __shfl_down(s2, off);
  }
  s = __shfl(s, 0);
  s2 = __shfl(s2, 0);
  const float mean = s * (1.f / 768.f);
  const float var = s2 * (1.f / 768.f) - mean * mean;
  const float inv = rsqrtf(var + 1e-5f);
  const int f32out = dual && *flag;
#pragma unroll
  for (int i = 0; i < 12; ++i) {
    const int c = lane + i * 64;
    const float val = (vbuf[i] - mean) * inv * b2f(g[c]) + b2f(bb[c]);
    if (f32out) ((float*)outv)[(size_t)row * D_ + c] = val;
    else ((u16*)outv)[(size_t)row * D_ + c] = f2b(val);
  }
}

// ---------------- host ----------------
extern "C" void kernel_launch(void* const* d_in, const int* in_sizes, int n_in,
                              void* d_out, int out_size, void* d_ws, size_t ws_size,
                              hipStream_t stream) {
  const void* x    = d_in[0];
  const void* pe   = d_in[1];
  const void* Wq   = d_in[2];
  const void* Wk   = d_in[3];
  const void* Wv   = d_in[4];
  const void* Wr   = d_in[5];
  const void* ub   = d_in[6];
  const void* vb   = d_in[7];
  const void* Wo   = d_in[8];
  const void* ln1g = d_in[9];
  const void* ln1b = d_in[10];
  const void* ln2g = d_in[11];
  const void* ln2b = d_in[12];
  const void* W1   = d_in[13];
  const void* b1   = d_in[14];
  const void* W2   = d_in[15];
  const void* b2   = d_in[16];
  char* ws = (char*)d_ws;

  constexpr int N_X  = B_ * S_ * D_;
  constexpr int N_PE = (2 * S_ - 1) * D_;

  constexpr size_t O_W   = 0;
  constexpr size_t O_SM  = 15335424;
  constexpr size_t O_XB  = 15368192;
  constexpr size_t O_QU  = 24805376;
  constexpr size_t O_QV  = 34242560;
  constexpr size_t O_KB  = 43679744;
  constexpr size_t O_VT  = 53116928;
  constexpr size_t O_RB  = 62554112;
  constexpr size_t NEEDED = 63733760;

  if (ws_size < NEEDED) {
    fill_sentinel<<<(out_size + 255) / 256, 256, 0, stream>>>((u16*)d_out, out_size);
    return;
  }

  int* flag = (int*)(ws + O_SM);
  u16* ubc  = (u16*)(ws + O_SM + 128);
  u16* vbc  = (u16*)(ws + O_SM + 1664);
  u16* b1c  = (u16*)(ws + O_SM + 3200);
  u16* b2c  = (u16*)(ws + O_SM + 9344);
  u16* g1c  = (u16*)(ws + O_SM + 10880);
  u16* be1c = (u16*)(ws + O_SM + 12416);
  u16* g2c  = (u16*)(ws + O_SM + 13952);
  u16* be2c = (u16*)(ws + O_SM + 15488);

  u16* wtq = (u16*)(ws + O_W);
  u16* wtk = wtq + (size_t)D_ * D_;
  u16* wtv = wtk + (size_t)D_ * D_;
  u16* wtr = wtv + (size_t)D_ * D_;
  u16* wto = wtr + (size_t)D_ * D_;
  u16* wt1 = wto + (size_t)D_ * D_;
  u16* wt2 = wt1 + (size_t)D_ * FF_;

  u16* xb  = (u16*)(ws + O_XB);
  u16* quB = (u16*)(ws + O_QU);
  u16* peb = (u16*)(ws + O_QV);
  u16* qvB = (u16*)(ws + O_QV);
  u16* kbB = (u16*)(ws + O_KB);
  u16* vtB = (u16*)(ws + O_VT);
  u16* rbB = (u16*)(ws + O_RB);
  u16* atB = (u16*)d_out;
  u16* y1B = xb;
  u16* x1B = (u16*)(ws + O_VT);
  u16* ffB = xb;
  u16* y2B = x1B;

  detect_dtype<<<1, 256, 0, stream>>>((const u16*)x, flag);
  convert_in4<<<(N_X / 4 + 255) / 256, 256, 0, stream>>>(x, xb, N_X / 4, flag);
  convert_in4<<<(N_PE / 4 + 255) / 256, 256, 0, stream>>>(pe, peb, N_PE / 4, flag);
  convert_small<<<33, 256, 0, stream>>>(b1, ub, vb, b2, ln1g, ln1b, ln2g, ln2b,
                                        b1c, ubc, vbc, b2c, g1c, be1c, g2c, be2c, flag);
  TP tp;
  tp.src[0] = Wq; tp.src[1] = Wk; tp.src[2] = Wv; tp.src[3] = Wr; tp.src[4] = Wo;
  tp.src[5] = W1; tp.src[6] = W2;
  tp.dst[0] = wtq; tp.dst[1] = wtk; tp.dst[2] = wtv; tp.dst[3] = wtr; tp.dst[4] = wto;
  tp.dst[5] = wt1; tp.dst[6] = wt2;
  transpose_all<<<7488, 256, 0, stream>>>(tp, flag);

  // r-proj: M=767 -> 64x64 tiles
  gemm3<64, 64, 32, 32, 0><<<dim3(12, 12), 256, 0, stream>>>(
      peb, wtr, rbB, nullptr, nullptr, nullptr, nullptr, nullptr, nullptr,
      2 * S_ - 1, D_, D_);
  // fused QKV: N=2304
  gemm3<128, 128, 64, 64, F_QKV><<<dim3(18, 48), 256, 0, stream>>>(
      xb, wtq, quB, qvB, kbB, vtB, ubc, vbc, nullptr, B_ * S_, 2304, D_);
  // attention -> d_out scratch (swizzled 1D grid)
  attn_kernel<<<4608, 256, 0, stream>>>(quB, qvB, kbB, vtB, rbB, atB);
  // Wo + residual
  gemm3<64, 128, 32, 64, F_RES><<<dim3(6, 96), 256, 0, stream>>>(
      atB, wto, y1B, nullptr, nullptr, nullptr, nullptr, nullptr, xb, B_ * S_, D_, D_);
  ln_kernel<<<B_ * S_ / 4, 256, 0, stream>>>(y1B, g1c, be1c, x1B, flag, 0);
  // FFN1
  gemm3<128, 128, 64, 64, F_BIAS | F_RELU><<<dim3(24, 48), 256, 0, stream>>>(
      x1B, wt1, ffB, nullptr, nullptr, nullptr, b1c, nullptr, nullptr, B_ * S_, FF_, D_);
  // FFN2
  gemm3<64, 128, 32, 64, F_BIAS | F_RES><<<dim3(6, 96), 256, 0, stream>>>(
      ffB, wt2, y2B, nullptr, nullptr, nullptr, b2c, nullptr, x1B, B_ * S_, D_, FF_);
  ln_kernel<<<B_ * S_ / 4, 256, 0, stream>>>(y2B, g2c, be2c, d_out, flag, 1);
}

// Round 7
// 462.240 us; speedup vs baseline: 1.3555x; 1.0088x over previous
//
#include <hip/hip_runtime.h>

typedef unsigned short u16;
typedef __attribute__((ext_vector_type(8))) short short8;
typedef __attribute__((ext_vector_type(4))) float floatx4;

#define B_  16
#define S_  384
#define D_  768
#define H_  12
#define DH_ 64
#define FF_ 3072

__device__ __forceinline__ float b2f(u16 h) { return __uint_as_float(((unsigned)h) << 16); }
__device__ __forceinline__ u16 f2b(float f) {
  unsigned u = __float_as_uint(f);
  u += 0x7fffu + ((u >> 16) & 1u);
  return (u16)(u >> 16);
}

__device__ __forceinline__ void gload16(const u16* g, u16* l) {
  __builtin_amdgcn_global_load_lds(
      (const __attribute__((address_space(1))) unsigned int*)g,
      (__attribute__((address_space(3))) unsigned int*)l, 16, 0, 0);
}

__global__ __launch_bounds__(256) void fill_sentinel(u16* out, int n) {
  int i = blockIdx.x * 256 + threadIdx.x;
  if (i < n) out[i] = 0x42DE;  // bf16 111.0
}

// ---------------- dtype detect ----------------
__global__ __launch_bounds__(256) void detect_dtype(const u16* __restrict__ x, int* flag) {
  __shared__ int cnt;
  if (threadIdx.x == 0) cnt = 0;
  __syncthreads();
  int c = 0;
  for (int i = threadIdx.x; i < 8192; i += 256) {
    const unsigned e = (x[i] >> 7) & 0xFFu;
    if (e >= 0xC0u) ++c;
  }
  atomicAdd(&cnt, c);
  __syncthreads();
  if (threadIdx.x == 0) *flag = (cnt > 64) ? 1 : 0;  // 1 = fp32 inputs
}

// ---------------- x/pe conversion, 4-wide ----------------
__global__ __launch_bounds__(256) void convert_in4(const void* __restrict__ src,
                                                   u16* __restrict__ dst, int n4,
                                                   const int* __restrict__ flag) {
  const int i = blockIdx.x * 256 + threadIdx.x;
  if (i >= n4) return;
  if (*flag) {
    const float4 f = ((const float4*)src)[i];
    ushort4 o;
    o.x = f2b(f.x); o.y = f2b(f.y); o.z = f2b(f.z); o.w = f2b(f.w);
    ((ushort4*)dst)[i] = o;
  } else {
    ((ushort4*)dst)[i] = ((const ushort4*)src)[i];
  }
}

// ---------------- all small tensors in one launch (8448 elems) ----------------
__global__ __launch_bounds__(256) void convert_small(
    const void* b1, const void* ub, const void* vb, const void* b2,
    const void* g1, const void* be1, const void* g2, const void* be2,
    u16* b1c, u16* ubc, u16* vbc, u16* b2c,
    u16* g1c, u16* be1c, u16* g2c, u16* be2c, const int* __restrict__ flag) {
  const int i = blockIdx.x * 256 + threadIdx.x;
  if (i >= 8448) return;
  const void* s; u16* d; int off;
  if (i < 3072) { s = b1; d = b1c; off = i; }
  else {
    const int r = i - 3072, sg = r / 768; off = r - sg * 768;
    switch (sg) {
      case 0: s = ub;  d = ubc;  break;
      case 1: s = vb;  d = vbc;  break;
      case 2: s = b2;  d = b2c;  break;
      case 3: s = g1;  d = g1c;  break;
      case 4: s = be1; d = be1c; break;
      case 5: s = g2;  d = g2c;  break;
      default: s = be2; d = be2c; break;
    }
  }
  d[off] = (*flag) ? f2b(((const float*)s)[off]) : ((const u16*)s)[off];
}

// ---------------- all 7 weight transposes in one launch ----------------
struct TP { const void* src[7]; u16* dst[7]; };
__global__ __launch_bounds__(256) void transpose_all(TP tp, const int* __restrict__ flag) {
  __shared__ u16 t[32][33];
  const int f32 = *flag;
  const int id = blockIdx.x;
  int w, tt, R, C, bc, br;
  if (id < 2880)      { w = id / 576; tt = id % 576;  R = 768;  C = 768;  bc = (tt % 24) * 32; br = (tt / 24) * 32; }
  else if (id < 5184) { w = 5;        tt = id - 2880; R = 768;  C = 3072; bc = (tt % 96) * 32; br = (tt / 96) * 32; }
  else                { w = 6;        tt = id - 5184; R = 3072; C = 768;  bc = (tt % 24) * 32; br = (tt / 24) * 32; }
  const void* in = tp.src[w];
  u16* out = tp.dst[w];
  const int tx = threadIdx.x & 31, ty = threadIdx.x >> 5;
  for (int i = ty; i < 32; i += 8) {
    const size_t idx = (size_t)(br + i) * C + bc + tx;
    t[i][tx] = f32 ? f2b(((const float*)in)[idx]) : ((const u16*)in)[idx];
  }
  __syncthreads();
  for (int i = ty; i < 32; i += 8) out[(size_t)(bc + i) * R + br + tx] = t[tx][i];
}

// ---------------- GEMM v3 (verified r5): XOR-swizzled LDS + prefetch ----------------
enum { F_BIAS = 1, F_RELU = 2, F_RES = 4, F_QKV = 8 };

template <int TM, int TN, int WM, int WN, int FLAGS>
__global__ __launch_bounds__(256) void gemm3(
    const u16* __restrict__ A, const u16* __restrict__ Bt,
    u16* __restrict__ out0, u16* __restrict__ out1,
    u16* __restrict__ out2, u16* __restrict__ out3,
    const u16* __restrict__ bias0, const u16* __restrict__ bias1,
    const u16* __restrict__ res, int M, int N, int K) {
  constexpr int WAVES_M = TM / WM;
  constexpr int MT = WM / 16, NT = WN / 16;
  constexpr int NI = (TM + TN) / 64;
  static_assert((TM / WM) * (TN / WN) == 4, "4 waves");
  __shared__ u16 SM[2][(TM + TN) * 32];

  const int m0 = blockIdx.y * TM;
  const int n0 = blockIdx.x * TN;
  const int tid = threadIdx.x;
  const int wid = tid >> 6, lane = tid & 63;
  const int wm = (wid % WAVES_M) * WM, wn = (wid / WAVES_M) * WN;
  const int lm = lane & 15, quad = lane >> 4;

  floatx4 acc[MT][NT];
#pragma unroll
  for (int i = 0; i < MT; ++i)
#pragma unroll
    for (int j = 0; j < NT; ++j) acc[i][j] = (floatx4){0.f, 0.f, 0.f, 0.f};

  const u16* srcs[NI];
  int ldso[NI];
#pragma unroll
  for (int i = 0; i < NI; ++i) {
    const int j = wid + 4 * i;
    const int r = j * 16 + (lane >> 2);
    const int q = (lane & 3) ^ ((r >> 1) & 3);
    const u16* p;
    if (r < TM) {
      int ga = m0 + r;
      if (ga > M - 1) ga = M - 1;
      p = A + (size_t)ga * K + q * 8;
    } else {
      p = Bt + (size_t)(n0 + r - TM) * K + q * 8;
    }
    srcs[i] = p;
    ldso[i] = j * 512;
  }
  const int slot = (quad ^ ((lm >> 1) & 3)) * 8;
  int aoff[MT], boff[NT];
#pragma unroll
  for (int t = 0; t < MT; ++t) aoff[t] = (wm + t * 16 + lm) * 32 + slot;
#pragma unroll
  for (int t = 0; t < NT; ++t) boff[t] = (TM + wn + t * 16 + lm) * 32 + slot;

#pragma unroll
  for (int i = 0; i < NI; ++i) gload16(srcs[i], &SM[0][ldso[i]]);
  __syncthreads();

  int buf = 0;
  for (int k0 = 0; k0 < K; k0 += 32, buf ^= 1) {
    if (k0 + 32 < K) {
      const int koff = (k0 + 32);
#pragma unroll
      for (int i = 0; i < NI; ++i) gload16(srcs[i] + koff, &SM[buf ^ 1][ldso[i]]);
    }
    short8 af[MT], bf[NT];
#pragma unroll
    for (int t = 0; t < MT; ++t) af[t] = *(const short8*)(&SM[buf][aoff[t]]);
#pragma unroll
    for (int t = 0; t < NT; ++t) bf[t] = *(const short8*)(&SM[buf][boff[t]]);
#pragma unroll
    for (int tm = 0; tm < MT; ++tm)
#pragma unroll
      for (int tn = 0; tn < NT; ++tn)
        acc[tm][tn] = __builtin_amdgcn_mfma_f32_16x16x32_bf16(af[tm], bf[tn], acc[tm][tn], 0, 0, 0);
    __syncthreads();
  }

#pragma unroll
  for (int tm = 0; tm < MT; ++tm) {
#pragma unroll
    for (int tn = 0; tn < NT; ++tn) {
      const int gcol = n0 + wn + tn * 16 + lm;
#pragma unroll
      for (int r = 0; r < 4; ++r) {
        const int grow = m0 + wm + tm * 16 + quad * 4 + r;
        if (grow >= M) continue;
        float val = acc[tm][tn][r];
        if (FLAGS & F_QKV) {
          const int region = gcol / 768;
          const int c = gcol - region * 768;
          if (region == 0) {
            out0[(size_t)grow * 768 + c] = f2b(val + b2f(bias0[c]));
            out1[(size_t)grow * 768 + c] = f2b(val + b2f(bias1[c]));
          } else if (region == 1) {
            out2[(size_t)grow * 768 + c] = f2b(val);
          } else {
            const int bb = grow / S_, s = grow - bb * S_;
            out3[((size_t)bb * D_ + c) * S_ + s] = f2b(val);
          }
        } else {
          if (FLAGS & F_BIAS) val += b2f(bias0[gcol]);
          if (FLAGS & F_RES) val += b2f(res[(size_t)grow * N + gcol]);
          if (FLAGS & F_RELU) val = fmaxf(val, 0.f);
          out0[(size_t)grow * N + gcol] = f2b(val);
        }
      }
    }
  }
}

// ---------------- attention v3: reg-prefetch, fused streams, 2 barriers ----------------
// grid: 4608 linear, swizzled so all 24 q-tiles of a (b,h) share id%8 (same XCD).
// LDS 37,952 B -> 4 blocks/CU. PV split by head-dim (no partial reduction).
__global__ __launch_bounds__(256, 4) void attn_kernel(
    const u16* __restrict__ qu, const u16* __restrict__ qv,
    const u16* __restrict__ kb, const u16* __restrict__ vt,
    const u16* __restrict__ rb, u16* __restrict__ attn) {
  __shared__ float scA[16 * 388];   // A_C scores fp32; P (bf16) overlaid per-row
  __shared__ u16 Eb[16 * 408];      // B_D dense, bf16
  __shared__ float rsum[16];

  const int id = blockIdx.x;
  const int g = id >> 3;
  const int qt = g % 24;
  const int bh = (id & 7) + 8 * (g / 24);
  const int b = bh / H_, h = bh % H_;
  const int i0 = qt * 16;
  const int tid = threadIdx.x, wid = tid >> 6, lane = tid & 63;
  const int lm = lane & 15, quad = lane >> 4;

  const size_t qrow = ((size_t)(b * S_ + i0 + lm)) * D_ + h * DH_;
  const short8 av0 = *(const short8*)(qv + qrow + quad * 8);
  const short8 av1 = *(const short8*)(qv + qrow + 32 + quad * 8);
  const short8 au0 = *(const short8*)(qu + qrow + quad * 8);
  const short8 au1 = *(const short8*)(qu + qrow + 32 + quad * 8);

  // ---- fused B_D (7 iters) + A_C (6 iters) with register double-buffer ----
  short8 r0, r1, k0, k1;
  {
    int t = i0 + wid * 16 + lm; if (t > 766) t = 766;
    const u16* p = rb + (size_t)t * D_ + h * DH_;
    r0 = *(const short8*)(p + quad * 8);
    r1 = *(const short8*)(p + 32 + quad * 8);
    const u16* q = kb + ((size_t)(b * S_ + wid * 96 + lm)) * D_ + h * DH_;
    k0 = *(const short8*)(q + quad * 8);
    k1 = *(const short8*)(q + 32 + quad * 8);
  }
#pragma unroll
  for (int i = 0; i < 7; ++i) {
    short8 nr0 = r0, nr1 = r1, nk0 = k0, nk1 = k1;
    const int ntt = wid + 4 * (i + 1);
    if (ntt < 25) {
      int t = i0 + ntt * 16 + lm; if (t > 766) t = 766;
      const u16* p = rb + (size_t)t * D_ + h * DH_;
      nr0 = *(const short8*)(p + quad * 8);
      nr1 = *(const short8*)(p + 32 + quad * 8);
    }
    if (i + 1 < 6) {
      const u16* q = kb + ((size_t)(b * S_ + (wid * 6 + i + 1) * 16 + lm)) * D_ + h * DH_;
      nk0 = *(const short8*)(q + quad * 8);
      nk1 = *(const short8*)(q + 32 + quad * 8);
    }
    const int tt = wid + 4 * i;
    if (tt < 25) {
      floatx4 e = (floatx4){0.f, 0.f, 0.f, 0.f};
      e = __builtin_amdgcn_mfma_f32_16x16x32_bf16(av0, r0, e, 0, 0, 0);
      e = __builtin_amdgcn_mfma_f32_16x16x32_bf16(av1, r1, e, 0, 0, 0);
#pragma unroll
      for (int r = 0; r < 4; ++r) Eb[(quad * 4 + r) * 408 + tt * 16 + lm] = f2b(e[r]);
    }
    if (i < 6) {
      floatx4 e = (floatx4){0.f, 0.f, 0.f, 0.f};
      e = __builtin_amdgcn_mfma_f32_16x16x32_bf16(au0, k0, e, 0, 0, 0);
      e = __builtin_amdgcn_mfma_f32_16x16x32_bf16(au1, k1, e, 0, 0, 0);
#pragma unroll
      for (int r = 0; r < 4; ++r) scA[(quad * 4 + r) * 388 + (wid * 6 + i) * 16 + lm] = e[r];
    }
    r0 = nr0; r1 = nr1; k0 = nk0; k1 = nk1;
  }
  __syncthreads();  // barrier 1

  // ---- V prefetch (latency hidden by softmax) ----
  short8 vv[12];
  const size_t vbase = ((size_t)(b * D_ + h * DH_ + wid * 16 + lm)) * S_;
#pragma unroll
  for (int kk = 0; kk < 12; ++kk)
    vv[kk] = *(const short8*)(vt + vbase + kk * 32 + quad * 8);

  // ---- softmax: row = wid*4+quad, 16 lm-lanes; shuffle reductions, 0 barriers ----
  u16* p16 = (u16*)scA;  // P[row][c] at u16 idx row*776 + c
  {
    const int row = wid * 4 + quad;
    float v[24];
    float lmax = -1e30f;
#pragma unroll
    for (int cc = 0; cc < 24; ++cc) {
      const int c = lm + cc * 16;
      const float s = (scA[row * 388 + c] + b2f(Eb[row * 408 + row + 383 - c])) * 0.125f;
      v[cc] = s;
      lmax = fmaxf(lmax, s);
    }
#pragma unroll
    for (int m = 1; m < 16; m <<= 1) lmax = fmaxf(lmax, __shfl_xor(lmax, m));
    float lsum = 0.f;
#pragma unroll
    for (int cc = 0; cc < 24; ++cc) {
      const float e = __expf(v[cc] - lmax);
      p16[row * 776 + lm + cc * 16] = f2b(e);
      lsum += e;
    }
#pragma unroll
    for (int m = 1; m < 16; m <<= 1) lsum += __shfl_xor(lsum, m);
    if (lm == 0) rsum[row] = lsum;
  }
  __syncthreads();  // barrier 2

  // ---- PV: wave w owns dh-slice [w*16, w*16+16), ALL 384 keys -> full sums ----
  floatx4 o = (floatx4){0.f, 0.f, 0.f, 0.f};
#pragma unroll
  for (int kk = 0; kk < 12; ++kk) {
    const short8 af = *(const short8*)(&p16[lm * 776 + kk * 32 + quad * 8]);
    o = __builtin_amdgcn_mfma_f32_16x16x32_bf16(af, vv[kk], o, 0, 0, 0);
  }
#pragma unroll
  for (int r = 0; r < 4; ++r) {
    const int row = quad * 4 + r;
    attn[((size_t)(b * S_ + i0 + row)) * D_ + h * DH_ + wid * 16 + lm] =
        f2b(o[r] / rsum[row]);
  }
}

// ---------------- row layernorm ----------------
__global__ __launch_bounds__(256) void ln_kernel(const u16* __restrict__ y,
                                                 const u16* __restrict__ g,
                                                 const u16* __restrict__ bb,
                                                 void* __restrict__ outv,
                                                 const int* __restrict__ flag, int dual) {
  const int row = blockIdx.x * 4 + (threadIdx.x >> 6);
  const int lane = threadIdx.x & 63;
  const u16* yr = y + (size_t)row * D_;
  float vbuf[12], s = 0.f, s2 = 0.f;
#pragma unroll
  for (int i = 0; i < 12; ++i) {
    const float x = b2f(yr[lane + i * 64]);
    vbuf[i] = x;
    s += x;
    s2 += x * x;
  }
#pragma unroll
  for (int off = 32; off; off >>= 1) {
    s += __shfl_down(s, off);
    s2 += __shfl_down(s2, off);
  }
  s = __shfl(s, 0);
  s2 = __shfl(s2, 0);
  const float mean = s * (1.f / 768.f);
  const float var = s2 * (1.f / 768.f) - mean * mean;
  const float inv = rsqrtf(var + 1e-5f);
  const int f32out = dual && *flag;
#pragma unroll
  for (int i = 0; i < 12; ++i) {
    const int c = lane + i * 64;
    const float val = (vbuf[i] - mean) * inv * b2f(g[c]) + b2f(bb[c]);
    if (f32out) ((float*)outv)[(size_t)row * D_ + c] = val;
    else ((u16*)outv)[(size_t)row * D_ + c] = f2b(val);
  }
}

// ---------------- host ----------------
extern "C" void kernel_launch(void* const* d_in, const int* in_sizes, int n_in,
                              void* d_out, int out_size, void* d_ws, size_t ws_size,
                              hipStream_t stream) {
  const void* x    = d_in[0];
  const void* pe   = d_in[1];
  const void* Wq   = d_in[2];
  const void* Wk   = d_in[3];
  const void* Wv   = d_in[4];
  const void* Wr   = d_in[5];
  const void* ub   = d_in[6];
  const void* vb   = d_in[7];
  const void* Wo   = d_in[8];
  const void* ln1g = d_in[9];
  const void* ln1b = d_in[10];
  const void* ln2g = d_in[11];
  const void* ln2b = d_in[12];
  const void* W1   = d_in[13];
  const void* b1   = d_in[14];
  const void* W2   = d_in[15];
  const void* b2   = d_in[16];
  char* ws = (char*)d_ws;

  constexpr int N_X  = B_ * S_ * D_;
  constexpr int N_PE = (2 * S_ - 1) * D_;

  constexpr size_t O_W   = 0;
  constexpr size_t O_SM  = 15335424;
  constexpr size_t O_XB  = 15368192;
  constexpr size_t O_QU  = 24805376;
  constexpr size_t O_QV  = 34242560;
  constexpr size_t O_KB  = 43679744;
  constexpr size_t O_VT  = 53116928;
  constexpr size_t O_RB  = 62554112;
  constexpr size_t NEEDED = 63733760;

  if (ws_size < NEEDED) {
    fill_sentinel<<<(out_size + 255) / 256, 256, 0, stream>>>((u16*)d_out, out_size);
    return;
  }

  int* flag = (int*)(ws + O_SM);
  u16* ubc  = (u16*)(ws + O_SM + 128);
  u16* vbc  = (u16*)(ws + O_SM + 1664);
  u16* b1c  = (u16*)(ws + O_SM + 3200);
  u16* b2c  = (u16*)(ws + O_SM + 9344);
  u16* g1c  = (u16*)(ws + O_SM + 10880);
  u16* be1c = (u16*)(ws + O_SM + 12416);
  u16* g2c  = (u16*)(ws + O_SM + 13952);
  u16* be2c = (u16*)(ws + O_SM + 15488);

  u16* wtq = (u16*)(ws + O_W);
  u16* wtk = wtq + (size_t)D_ * D_;
  u16* wtv = wtk + (size_t)D_ * D_;
  u16* wtr = wtv + (size_t)D_ * D_;
  u16* wto = wtr + (size_t)D_ * D_;
  u16* wt1 = wto + (size_t)D_ * D_;
  u16* wt2 = wt1 + (size_t)D_ * FF_;

  u16* xb  = (u16*)(ws + O_XB);
  u16* quB = (u16*)(ws + O_QU);
  u16* peb = (u16*)(ws + O_QV);
  u16* qvB = (u16*)(ws + O_QV);
  u16* kbB = (u16*)(ws + O_KB);
  u16* vtB = (u16*)(ws + O_VT);
  u16* rbB = (u16*)(ws + O_RB);
  u16* atB = (u16*)d_out;
  u16* y1B = xb;
  u16* x1B = (u16*)(ws + O_VT);
  u16* ffB = xb;
  u16* y2B = x1B;

  detect_dtype<<<1, 256, 0, stream>>>((const u16*)x, flag);
  convert_in4<<<(N_X / 4 + 255) / 256, 256, 0, stream>>>(x, xb, N_X / 4, flag);
  convert_in4<<<(N_PE / 4 + 255) / 256, 256, 0, stream>>>(pe, peb, N_PE / 4, flag);
  convert_small<<<33, 256, 0, stream>>>(b1, ub, vb, b2, ln1g, ln1b, ln2g, ln2b,
                                        b1c, ubc, vbc, b2c, g1c, be1c, g2c, be2c, flag);
  TP tp;
  tp.src[0] = Wq; tp.src[1] = Wk; tp.src[2] = Wv; tp.src[3] = Wr; tp.src[4] = Wo;
  tp.src[5] = W1; tp.src[6] = W2;
  tp.dst[0] = wtq; tp.dst[1] = wtk; tp.dst[2] = wtv; tp.dst[3] = wtr; tp.dst[4] = wto;
  tp.dst[5] = wt1; tp.dst[6] = wt2;
  transpose_all<<<7488, 256, 0, stream>>>(tp, flag);

  // r-proj: M=767 -> 64x64 tiles
  gemm3<64, 64, 32, 32, 0><<<dim3(12, 12), 256, 0, stream>>>(
      peb, wtr, rbB, nullptr, nullptr, nullptr, nullptr, nullptr, nullptr,
      2 * S_ - 1, D_, D_);
  // fused QKV: N=2304
  gemm3<128, 128, 64, 64, F_QKV><<<dim3(18, 48), 256, 0, stream>>>(
      xb, wtq, quB, qvB, kbB, vtB, ubc, vbc, nullptr, B_ * S_, 2304, D_);
  // attention -> d_out scratch (swizzled 1D grid)
  attn_kernel<<<4608, 256, 0, stream>>>(quB, qvB, kbB, vtB, rbB, atB);
  // Wo + residual
  gemm3<64, 128, 32, 64, F_RES><<<dim3(6, 96), 256, 0, stream>>>(
      atB, wto, y1B, nullptr, nullptr, nullptr, nullptr, nullptr, xb, B_ * S_, D_, D_);
  ln_kernel<<<B_ * S_ / 4, 256, 0, stream>>>(y1B, g1c, be1c, x1B, flag, 0);
  // FFN1
  gemm3<128, 128, 64, 64, F_BIAS | F_RELU><<<dim3(24, 48), 256, 0, stream>>>(
      x1B, wt1, ffB, nullptr, nullptr, nullptr, b1c, nullptr, nullptr, B_ * S_, FF_, D_);
  // FFN2
  gemm3<64, 128, 32, 64, F_BIAS | F_RES><<<dim3(6, 96), 256, 0, stream>>>(
      ffB, wt2, y2B, nullptr, nullptr, nullptr, b2c, nullptr, x1B, B_ * S_, D_, FF_);
  ln_kernel<<<B_ * S_ / 4, 256, 0, stream>>>(y2B, g2c, be2c, d_out, flag, 1);
}